// Round 1
// baseline (62.668 us; speedup 1.0000x reference)
//
#include <hip/hip_runtime.h>

#define ROWS 16
#define NN 2048
#define TOTAL_ROWS 8192              // B*N = 4*2048
#define HALF 16777216ull             // B*N*N

// ---------------- Kernel A: shift[row] = 7 * (k_net(x_row) + b_kp) ----------------
// h1 = relu(x @ W_mu1 + b_mu1)   [128 -> 256]
// h2 = h1 @ W_mu2 + b_mu2        [256 -> 256]
// shift = 7 * (h2 . W_kp + b_kp)
// 16 rows per block, 256 threads. Thread (tr = t>>6, tc = t&63) computes
// rows tr*4..tr*4+3  x  cols {tc, tc+64, tc+128, tc+192}  (4x4 micro-tile).
__global__ __launch_bounds__(256) void mlp_shift_kernel(
    const float* __restrict__ x,
    const float* __restrict__ Wmu1, const float* __restrict__ bmu1,
    const float* __restrict__ Wmu2, const float* __restrict__ bmu2,
    const float* __restrict__ Wkp,  const float* __restrict__ bkp,
    float* __restrict__ shift)
{
    __shared__ float xs[128][20];   // transposed x tile [d][r], pad 20 for bank spread
    __shared__ float h1[256][20];   // transposed h1 [c][r]

    const int t = threadIdx.x;
    const int row0 = blockIdx.x * ROWS;

    // stage x rows, transposed: thread t loads row r = t>>4, d-chunk dq = t&15 (8 floats)
    {
        const int r = t >> 4, dq = t & 15;
        const float* src = x + (size_t)(row0 + r) * 128 + dq * 8;
        const float4 v0 = *(const float4*)(src);
        const float4 v1 = *(const float4*)(src + 4);
        const int d0 = dq * 8;
        xs[d0 + 0][r] = v0.x; xs[d0 + 1][r] = v0.y;
        xs[d0 + 2][r] = v0.z; xs[d0 + 3][r] = v0.w;
        xs[d0 + 4][r] = v1.x; xs[d0 + 5][r] = v1.y;
        xs[d0 + 6][r] = v1.z; xs[d0 + 7][r] = v1.w;
    }
    __syncthreads();

    const int tc = t & 63;
    const int tr = t >> 6;   // wave index: each wave owns 4 rows, reduces over tc

    float acc[4][4];
    #pragma unroll
    for (int i = 0; i < 4; ++i)
        #pragma unroll
        for (int j = 0; j < 4; ++j) acc[i][j] = 0.f;

    // layer 1: 128-deep
    for (int d = 0; d < 128; ++d) {
        const float4 av = *(const float4*)&xs[d][tr * 4];   // broadcast (wave-uniform addr)
        const float ar[4] = {av.x, av.y, av.z, av.w};
        const float* wrow = Wmu1 + d * 256 + tc;
        const float w[4] = {wrow[0], wrow[64], wrow[128], wrow[192]};
        #pragma unroll
        for (int rr = 0; rr < 4; ++rr)
            #pragma unroll
            for (int j = 0; j < 4; ++j)
                acc[rr][j] = fmaf(ar[rr], w[j], acc[rr][j]);
    }

    // bias + relu -> h1 transposed
    #pragma unroll
    for (int j = 0; j < 4; ++j) {
        const int c = tc + 64 * j;
        const float bc = bmu1[c];
        #pragma unroll
        for (int rr = 0; rr < 4; ++rr)
            h1[c][tr * 4 + rr] = fmaxf(acc[rr][j] + bc, 0.f);
    }
    __syncthreads();

    float acc2[4][4];
    #pragma unroll
    for (int i = 0; i < 4; ++i)
        #pragma unroll
        for (int j = 0; j < 4; ++j) acc2[i][j] = 0.f;

    // layer 2: 256-deep
    for (int k = 0; k < 256; ++k) {
        const float4 av = *(const float4*)&h1[k][tr * 4];
        const float ar[4] = {av.x, av.y, av.z, av.w};
        const float* wrow = Wmu2 + k * 256 + tc;
        const float w[4] = {wrow[0], wrow[64], wrow[128], wrow[192]};
        #pragma unroll
        for (int rr = 0; rr < 4; ++rr)
            #pragma unroll
            for (int j = 0; j < 4; ++j)
                acc2[rr][j] = fmaf(ar[rr], w[j], acc2[rr][j]);
    }

    // bias + dot with W_kp, partial per lane
    float p[4] = {0.f, 0.f, 0.f, 0.f};
    #pragma unroll
    for (int j = 0; j < 4; ++j) {
        const int c = tc + 64 * j;
        const float wk = Wkp[c];
        const float bc = bmu2[c];
        #pragma unroll
        for (int rr = 0; rr < 4; ++rr)
            p[rr] += (acc2[rr][j] + bc) * wk;
    }
    // wave (64-lane) butterfly reduce over tc
    #pragma unroll
    for (int off = 32; off > 0; off >>= 1) {
        #pragma unroll
        for (int rr = 0; rr < 4; ++rr)
            p[rr] += __shfl_xor(p[rr], off, 64);
    }
    if (tc == 0) {
        const float bk = bkp[0];
        #pragma unroll
        for (int rr = 0; rr < 4; ++rr)
            shift[row0 + tr * 4 + rr] = 7.0f * (p[rr] + bk);
    }
}

// ---------------- Kernel B: fill outputs ----------------
// out[0      .. HALF)  : adj[b,i,j] = sigmoid((2 - 7j) + shift[b,i])
// out[HALF .. 2*HALF)  : idxs[b,i,j] = (float)j   (stable argsort of all-ties = identity)
__global__ __launch_bounds__(256) void fill_kernel(
    const float* __restrict__ shift, float* __restrict__ out)
{
    const int row = blockIdx.x;               // 0..8191
    const float s = shift[row];
    const int j0 = threadIdx.x * 8;           // 256 threads * 8 = 2048

    float a[8], ix[8];
    #pragma unroll
    for (int i = 0; i < 8; ++i) {
        const int j = j0 + i;
        const float z = (2.0f - 7.0f * (float)j) + s;
        a[i]  = 1.0f / (1.0f + __expf(-z));
        ix[i] = (float)j;
    }

    float* adj = out + (size_t)row * NN;
    float* idx = out + HALF + (size_t)row * NN;
    *(float4*)(adj + j0)     = make_float4(a[0], a[1], a[2], a[3]);
    *(float4*)(adj + j0 + 4) = make_float4(a[4], a[5], a[6], a[7]);
    *(float4*)(idx + j0)     = make_float4(ix[0], ix[1], ix[2], ix[3]);
    *(float4*)(idx + j0 + 4) = make_float4(ix[4], ix[5], ix[6], ix[7]);
}

extern "C" void kernel_launch(void* const* d_in, const int* in_sizes, int n_in,
                              void* d_out, int out_size, void* d_ws, size_t ws_size,
                              hipStream_t stream)
{
    (void)in_sizes; (void)n_in; (void)out_size; (void)ws_size;
    const float* x    = (const float*)d_in[0];
    // d_in[1] temp, d_in[2] W_in, d_in[3] b_in, d_in[4] w_dist, d_in[5] b_dist: dead code
    const float* Wmu1 = (const float*)d_in[6];
    const float* bmu1 = (const float*)d_in[7];
    const float* Wmu2 = (const float*)d_in[8];
    const float* bmu2 = (const float*)d_in[9];
    const float* Wkp  = (const float*)d_in[10];
    const float* bkp  = (const float*)d_in[11];

    float* shift = (float*)d_ws;              // 8192 floats
    float* out   = (float*)d_out;

    hipLaunchKernelGGL(mlp_shift_kernel, dim3(TOTAL_ROWS / ROWS), dim3(256), 0, stream,
                       x, Wmu1, bmu1, Wmu2, bmu2, Wkp, bkp, shift);
    hipLaunchKernelGGL(fill_kernel, dim3(TOTAL_ROWS), dim3(256), 0, stream,
                       shift, out);
}